// Round 2
// baseline (35.535 us; speedup 1.0000x reference)
//
#include <hip/hip_runtime.h>
#include <math.h>

#define H_DIM 1024
#define N_DIM 64
#define L_DIM 2048
#define CHUNK 8
#define NTHREADS 256   // NTHREADS * CHUNK == L_DIM

// Hardware transcendentals. v_sin/v_cos take input in REVOLUTIONS
// (D = sin(S0 * 2pi)); v_exp computes 2^x.
__device__ __forceinline__ float exp2_hw(float x) {
#if __has_builtin(__builtin_amdgcn_exp2f)
    return __builtin_amdgcn_exp2f(x);
#else
    float o; asm("v_exp_f32 %0, %1" : "=v"(o) : "v"(x)); return o;
#endif
}
__device__ __forceinline__ float sin_rev(float x) {
#if __has_builtin(__builtin_amdgcn_sinf)
    return __builtin_amdgcn_sinf(x);
#else
    float o; asm("v_sin_f32 %0, %1" : "=v"(o) : "v"(x)); return o;
#endif
}
__device__ __forceinline__ float cos_rev(float x) {
#if __has_builtin(__builtin_amdgcn_cosf)
    return __builtin_amdgcn_cosf(x);
#else
    float o; asm("v_cos_f32 %0, %1" : "=v"(o) : "v"(x)); return o;
#endif
}

__global__ __launch_bounds__(NTHREADS)
void lssl_kernel(const float* __restrict__ Lre, const float* __restrict__ Lim,
                 const float* __restrict__ Bre, const float* __restrict__ Bim,
                 const float* __restrict__ Cre, const float* __restrict__ Cim,
                 const float* __restrict__ Dv,  const float* __restrict__ log_dt,
                 float* __restrict__ out)
{
    const int h = blockIdx.x;
    const int t = threadIdx.x;

    // per-n params: s_aw[n] = (a_re, a_im, w_re, w_im), w = C*b_bar
    //               s_pol[n] = (log2|a|, arg(a)/2pi)
    __shared__ float4 s_aw[N_DIM];
    __shared__ float2 s_pol[N_DIM];

    if (t < N_DIM) {
        const int   n   = t;
        const int   idx = h * N_DIM + n;
        const float dt  = expf(log_dt[h]);
        const float lre = Lre[idx];
        const float lim = Lim[idx];
        const float sp  = log1pf(expf(lre));     // softplus
        const float hr  = -0.5f * dt * sp;       // Re(half)
        const float hi  =  0.5f * dt * lim;      // Im(half)
        const float dr  = 1.0f - hr;             // denom = (dr, -hi)
        const float inv = 1.0f / (dr * dr + hi * hi);
        const float xr  = 1.0f + hr;
        const float ar  = (xr * dr - hi * hi) * inv;
        const float ai  = 2.0f * hi * inv;
        const float tr  = dt * dr * inv;
        const float ti  = dt * hi * inv;
        const float bre = Bre[idx], bim = Bim[idx];
        const float br  = tr * bre - ti * bim;
        const float bi  = tr * bim + ti * bre;
        const float cre = Cre[idx], cim = Cim[idx];
        const float wr  = cre * br - cim * bi;
        const float wi  = cre * bi + cim * br;

        const float m2   = ar * ar + ai * ai;
        const float lg2A = 0.5f * log2f(m2);                        // log2|a|
        const float thRv = atan2f(ai, ar) * 0.15915494309189535f;   // arg/2pi

        s_aw[n]  = make_float4(ar, ai, wr, wi);
        s_pol[n] = make_float2(lg2A, thRv);
    }
    __syncthreads();

    const float l0f = (float)(t * CHUNK);
    float acc[CHUNK];
#pragma unroll
    for (int j = 0; j < CHUNK; ++j) acc[j] = 0.0f;

#define COMPUTE(aw, pl)                                            \
    {                                                              \
        const float mag = exp2_hw(l0f * (pl).x);                   \
        float rv = l0f * (pl).y;                                   \
        rv -= floorf(rv);                                          \
        const float s = sin_rev(rv);                               \
        const float c = cos_rev(rv);                               \
        float pr = mag * ((aw).z * c - (aw).w * s);                \
        float pi = mag * ((aw).z * s + (aw).w * c);                \
        _Pragma("unroll")                                          \
        for (int j = 0; j < CHUNK; ++j) {                          \
            acc[j] += pr;                                          \
            const float npr = pr * (aw).x - pi * (aw).y;           \
            pi = pr * (aw).y + pi * (aw).x;                        \
            pr = npr;                                              \
        }                                                          \
    }

    // software-pipelined over n: params for iteration k+1 are loaded
    // one full COMPUTE (~140 cy) before use, hiding LDS latency.
    float4 aw0 = s_aw[0];
    float2 pl0 = s_pol[0];
#pragma unroll 2
    for (int n = 0; n < N_DIM; n += 2) {
        const float4 aw1 = s_aw[n + 1];
        const float2 pl1 = s_pol[n + 1];
        COMPUTE(aw0, pl0)
        aw0 = s_aw[(n + 2) & (N_DIM - 1)];
        pl0 = s_pol[(n + 2) & (N_DIM - 1)];
        COMPUTE(aw1, pl1)
    }
#undef COMPUTE

    float* orow = out + (size_t)h * L_DIM + (size_t)t * CHUNK;
    *reinterpret_cast<float4*>(orow)     = make_float4(acc[0], acc[1], acc[2], acc[3]);
    *reinterpret_cast<float4*>(orow + 4) = make_float4(acc[4], acc[5], acc[6], acc[7]);

    if (t == 0) out[(size_t)H_DIM * L_DIM + h] = Dv[h];
}

extern "C" void kernel_launch(void* const* d_in, const int* in_sizes, int n_in,
                              void* d_out, int out_size, void* d_ws, size_t ws_size,
                              hipStream_t stream) {
    const float* Lre   = (const float*)d_in[0];
    const float* Lim   = (const float*)d_in[1];
    const float* Bre   = (const float*)d_in[2];
    const float* Bim   = (const float*)d_in[3];
    const float* Cre   = (const float*)d_in[4];
    const float* Cim   = (const float*)d_in[5];
    const float* Dv    = (const float*)d_in[6];
    const float* logdt = (const float*)d_in[7];
    float* out = (float*)d_out;

    lssl_kernel<<<dim3(H_DIM), dim3(NTHREADS), 0, stream>>>(
        Lre, Lim, Bre, Bim, Cre, Cim, Dv, logdt, out);
}

// Round 3
// 27.063 us; speedup vs baseline: 1.3130x; 1.3130x over previous
//
#include <hip/hip_runtime.h>
#include <math.h>

#define H_DIM 1024
#define N_DIM 64
#define L_DIM 2048
#define CHUNK 8
#define NT_MAIN 256   // NT_MAIN * CHUNK == L_DIM
#define NT_SETUP 256

// Hardware transcendentals: v_sin/v_cos take REVOLUTIONS (D=sin(2pi*S0)),
// v_exp_f32 computes 2^x, v_fract_f32 is x-floor(x).
__device__ __forceinline__ float exp2_hw(float x) {
    float o; asm("v_exp_f32 %0, %1" : "=v"(o) : "v"(x)); return o;
}
__device__ __forceinline__ float sin_rev(float x) {
    float o; asm("v_sin_f32 %0, %1" : "=v"(o) : "v"(x)); return o;
}
__device__ __forceinline__ float cos_rev(float x) {
    float o; asm("v_cos_f32 %0, %1" : "=v"(o) : "v"(x)); return o;
}
__device__ __forceinline__ float fract_hw(float x) {
    float o; asm("v_fract_f32 %0, %1" : "=v"(o) : "v"(x)); return o;
}

// Per-(h,n) parameter precompute. P[idx*2+0] = (log2|a|, arg(a)/2pi, wr, wi)
//                                 P[idx*2+1] = (2*Re(a), |a|^2, wr2, wi2)
// with w = C*b_bar and w2 = w*a (lets x1 reuse the same mag/sin/cos as x0).
__global__ __launch_bounds__(NT_SETUP)
void lssl_setup(const float* __restrict__ Lre, const float* __restrict__ Lim,
                const float* __restrict__ Bre, const float* __restrict__ Bim,
                const float* __restrict__ Cre, const float* __restrict__ Cim,
                const float* __restrict__ log_dt, float4* __restrict__ P)
{
    const int idx = blockIdx.x * NT_SETUP + threadIdx.x;   // (h,n) flat
    const int h   = idx >> 6;

    const float dt  = expf(log_dt[h]);
    const float lre = Lre[idx];
    const float lim = Lim[idx];
    const float sp  = log1pf(expf(lre));     // softplus
    const float hr  = -0.5f * dt * sp;       // Re(half)
    const float hi  =  0.5f * dt * lim;      // Im(half)
    const float dr  = 1.0f - hr;             // denom = (dr, -hi)
    const float inv = 1.0f / (dr * dr + hi * hi);
    const float xr  = 1.0f + hr;
    const float ar  = (xr * dr - hi * hi) * inv;   // a_bar
    const float ai  = 2.0f * hi * inv;
    const float tr  = dt * dr * inv;               // dt/denom
    const float ti  = dt * hi * inv;
    const float bre = Bre[idx], bim = Bim[idx];
    const float br  = tr * bre - ti * bim;         // b_bar
    const float bi  = tr * bim + ti * bre;
    const float cre = Cre[idx], cim = Cim[idx];
    const float wr  = cre * br - cim * bi;         // w = C*b_bar
    const float wi  = cre * bi + cim * br;
    const float wr2 = wr * ar - wi * ai;           // w2 = w*a
    const float wi2 = wr * ai + wi * ar;

    const float m2   = ar * ar + ai * ai;
    const float lg2A = 0.5f * log2f(m2);
    const float thRv = atan2f(ai, ar) * 0.15915494309189535f;

    P[idx * 2 + 0] = make_float4(lg2A, thRv, wr, wi);
    P[idx * 2 + 1] = make_float4(ar + ar, m2, wr2, wi2);
}

// Main: thread t of block h owns l = t*8 .. t*8+7.
// x0 = Re(w a^{l0}), x1 = Re(w2 a^{l0}) = Re(w a^{l0+1}) from one polar eval;
// then x_{j} = 2Re(a)*x_{j-1} - |a|^2*x_{j-2}  (3 VALU / element).
__global__ __launch_bounds__(NT_MAIN)
void lssl_main(const float4* __restrict__ P, const float* __restrict__ Dv,
               float* __restrict__ out)
{
    const int h = blockIdx.x;
    const int t = threadIdx.x;
    const float l0f = (float)(t * CHUNK);

    float acc[CHUNK];
#pragma unroll
    for (int j = 0; j < CHUNK; ++j) acc[j] = 0.0f;

    const float4* Ph = P + (size_t)h * (N_DIM * 2);   // block-uniform

#pragma unroll 4
    for (int n = 0; n < N_DIM; ++n) {
        const float4 p0 = Ph[2 * n + 0];
        const float4 p1 = Ph[2 * n + 1];
        const float mag = exp2_hw(l0f * p0.x);
        const float rv  = fract_hw(l0f * p0.y);
        const float s   = sin_rev(rv);
        const float c   = cos_rev(rv);
        float x0 = mag * fmaf(p0.z, c, -(p0.w * s));
        float x1 = mag * fmaf(p1.z, c, -(p1.w * s));
        acc[0] += x0;
        acc[1] += x1;
#pragma unroll
        for (int j = 2; j < CHUNK; ++j) {
            const float x2 = fmaf(p1.x, x1, -(p1.y * x0));
            acc[j] += x2;
            x0 = x1;
            x1 = x2;
        }
    }

    float* orow = out + (size_t)h * L_DIM + (size_t)t * CHUNK;
    *reinterpret_cast<float4*>(orow)     = make_float4(acc[0], acc[1], acc[2], acc[3]);
    *reinterpret_cast<float4*>(orow + 4) = make_float4(acc[4], acc[5], acc[6], acc[7]);

    if (t == 0) out[(size_t)H_DIM * L_DIM + h] = Dv[h];
}

extern "C" void kernel_launch(void* const* d_in, const int* in_sizes, int n_in,
                              void* d_out, int out_size, void* d_ws, size_t ws_size,
                              hipStream_t stream) {
    const float* Lre   = (const float*)d_in[0];
    const float* Lim   = (const float*)d_in[1];
    const float* Bre   = (const float*)d_in[2];
    const float* Bim   = (const float*)d_in[3];
    const float* Cre   = (const float*)d_in[4];
    const float* Cim   = (const float*)d_in[5];
    const float* Dv    = (const float*)d_in[6];
    const float* logdt = (const float*)d_in[7];
    float* out   = (float*)d_out;
    float4* P    = (float4*)d_ws;   // 1024*64*2 float4 = 2 MiB

    lssl_setup<<<dim3((H_DIM * N_DIM) / NT_SETUP), dim3(NT_SETUP), 0, stream>>>(
        Lre, Lim, Bre, Bim, Cre, Cim, logdt, P);
    lssl_main<<<dim3(H_DIM), dim3(NT_MAIN), 0, stream>>>(P, Dv, out);
}

// Round 4
// 20.784 us; speedup vs baseline: 1.7097x; 1.3021x over previous
//
#include <hip/hip_runtime.h>
#include <math.h>

#define H_DIM 1024
#define N_DIM 64
#define L_DIM 2048
#define CHUNK 8
#define NT 256   // NT * CHUNK == L_DIM

typedef float f32x2 __attribute__((ext_vector_type(2)));
typedef float f32x4 __attribute__((ext_vector_type(4)));

// HW transcendentals: v_sin/v_cos take REVOLUTIONS, v_exp_f32 is 2^x,
// v_fract_f32 is x - floor(x) (full-rate VALU).
__device__ __forceinline__ float exp2_hw(float x) {
    float o; asm("v_exp_f32 %0, %1" : "=v"(o) : "v"(x)); return o;
}
__device__ __forceinline__ float sin_rev(float x) {
    float o; asm("v_sin_f32 %0, %1" : "=v"(o) : "v"(x)); return o;
}
__device__ __forceinline__ float cos_rev(float x) {
    float o; asm("v_cos_f32 %0, %1" : "=v"(o) : "v"(x)); return o;
}
__device__ __forceinline__ float fract_hw(float x) {
    float o; asm("v_fract_f32 %0, %1" : "=v"(o) : "v"(x)); return o;
}

// Packed f32 (VOP3P) — full rate on CDNA: 2 f32 ops per instruction.
__device__ __forceinline__ f32x2 pk_mul(f32x2 a, f32x2 b) {
    f32x2 d; asm("v_pk_mul_f32 %0, %1, %2" : "=v"(d) : "v"(a), "v"(b)); return d;
}
__device__ __forceinline__ f32x2 pk_add(f32x2 a, f32x2 b) {
    f32x2 d; asm("v_pk_add_f32 %0, %1, %2" : "=v"(d) : "v"(a), "v"(b)); return d;
}
// a*b - c (fused):
__device__ __forceinline__ f32x2 pk_fms(f32x2 a, f32x2 b, f32x2 c) {
    f32x2 d;
    asm("v_pk_fma_f32 %0, %1, %2, %3 neg_lo:[0,0,1] neg_hi:[0,0,1]"
        : "=v"(d) : "v"(a), "v"(b), "v"(c));
    return d;
}
__device__ __forceinline__ f32x2 splat(float x) { f32x2 r; r[0] = x; r[1] = x; return r; }

// Per block h: thread t owns l = 8t..8t+7.
//   x_l = Re(w a^l), w = C*b_bar.
//   Seeds x0..x3 from ONE polar eval using w*a^k, k=0..3 (packed pairs).
//   Then packed stride-2 recurrence: (x_{2j},x_{2j+1}) = c2*prev - m4*prevprev,
//   c2 = 2Re(a^2), m4 = |a|^4  ->  1.5 VALU per element.
__global__ __launch_bounds__(NT, 4)
void lssl_kernel(const float* __restrict__ Lre, const float* __restrict__ Lim,
                 const float* __restrict__ Bre, const float* __restrict__ Bim,
                 const float* __restrict__ Cre, const float* __restrict__ Cim,
                 const float* __restrict__ Dv,  const float* __restrict__ log_dt,
                 float* __restrict__ out)
{
    const int h = blockIdx.x;
    const int t = threadIdx.x;

    __shared__ f32x4 sW0[N_DIM];  // (wr, wr2, wi, wi2)   : w, w*a
    __shared__ f32x4 sW1[N_DIM];  // (wr3, wr4, wi3, wi4) : w*a^2, w*a^3
    __shared__ f32x4 sCM[N_DIM];  // (c2, c2, m4, m4)
    __shared__ f32x2 sPL[N_DIM];  // (log2|a|, arg(a)/2pi)

    if (t < N_DIM) {
        const int   idx = h * N_DIM + t;
        const float dt  = expf(log_dt[h]);
        const float lre = Lre[idx];
        const float lim = Lim[idx];
        const float sp  = log1pf(expf(lre));     // softplus
        const float hr  = -0.5f * dt * sp;
        const float hi  =  0.5f * dt * lim;
        const float dr  = 1.0f - hr;             // denom = (dr, -hi)
        const float inv = 1.0f / (dr * dr + hi * hi);
        const float xr  = 1.0f + hr;
        const float ar  = (xr * dr - hi * hi) * inv;   // a_bar
        const float ai  = 2.0f * hi * inv;
        const float tr  = dt * dr * inv;
        const float ti  = dt * hi * inv;
        const float bre = Bre[idx], bim = Bim[idx];
        const float br  = tr * bre - ti * bim;         // b_bar
        const float bi  = tr * bim + ti * bre;
        const float cre = Cre[idx], cim = Cim[idx];
        const float wr  = cre * br - cim * bi;         // w = C*b_bar
        const float wi  = cre * bi + cim * br;
        const float wr2 = wr * ar - wi * ai;           // w*a
        const float wi2 = wr * ai + wi * ar;
        const float wr3 = wr2 * ar - wi2 * ai;         // w*a^2
        const float wi3 = wr2 * ai + wi2 * ar;
        const float wr4 = wr3 * ar - wi3 * ai;         // w*a^3
        const float wi4 = wr3 * ai + wi3 * ar;

        const float m2   = ar * ar + ai * ai;
        const float c2   = 2.0f * (ar * ar - ai * ai); // 2*Re(a^2)
        const float m4   = m2 * m2;
        const float lg2A = 0.5f * log2f(m2);
        const float thRv = atan2f(ai, ar) * 0.15915494309189535f;

        sW0[t] = (f32x4){wr, wr2, wi, wi2};
        sW1[t] = (f32x4){wr3, wr4, wi3, wi4};
        sCM[t] = (f32x4){c2, c2, m4, m4};
        sPL[t] = (f32x2){lg2A, thRv};
    }
    __syncthreads();

    const float l0f = (float)(t * CHUNK);
    f32x2 acc0 = {0.f, 0.f}, acc1 = {0.f, 0.f}, acc2 = {0.f, 0.f}, acc3 = {0.f, 0.f};

#pragma unroll 4
    for (int n = 0; n < N_DIM; ++n) {
        const f32x2 pl  = sPL[n];
        const float mag = exp2_hw(l0f * pl[0]);
        const float rv  = fract_hw(l0f * pl[1]);
        const float s   = sin_rev(rv);
        const float c   = cos_rev(rv);
        const float mc  = mag * c;
        const float ms  = mag * s;
        const f32x2 MC  = splat(mc);
        const f32x2 MS  = splat(ms);

        const f32x4 w0 = sW0[n], w1 = sW1[n], cm = sCM[n];
        const f32x2 WR0 = {w0[0], w0[1]}, WI0 = {w0[2], w0[3]};
        const f32x2 WR1 = {w1[0], w1[1]}, WI1 = {w1[2], w1[3]};
        const f32x2 C2  = {cm[0], cm[1]}, M4  = {cm[2], cm[3]};

        const f32x2 y0 = pk_fms(WR0, MC, pk_mul(WI0, MS));   // (x0,x1)
        const f32x2 y1 = pk_fms(WR1, MC, pk_mul(WI1, MS));   // (x2,x3)
        acc0 = pk_add(acc0, y0);
        acc1 = pk_add(acc1, y1);
        const f32x2 y2 = pk_fms(C2, y1, pk_mul(M4, y0));     // (x4,x5)
        acc2 = pk_add(acc2, y2);
        const f32x2 y3 = pk_fms(C2, y2, pk_mul(M4, y1));     // (x6,x7)
        acc3 = pk_add(acc3, y3);
    }

    float* orow = out + (size_t)h * L_DIM + (size_t)t * CHUNK;
    *reinterpret_cast<float4*>(orow) =
        make_float4(acc0[0], acc0[1], acc1[0], acc1[1]);
    *reinterpret_cast<float4*>(orow + 4) =
        make_float4(acc2[0], acc2[1], acc3[0], acc3[1]);

    if (t == 0) out[(size_t)H_DIM * L_DIM + h] = Dv[h];
}

extern "C" void kernel_launch(void* const* d_in, const int* in_sizes, int n_in,
                              void* d_out, int out_size, void* d_ws, size_t ws_size,
                              hipStream_t stream) {
    const float* Lre   = (const float*)d_in[0];
    const float* Lim   = (const float*)d_in[1];
    const float* Bre   = (const float*)d_in[2];
    const float* Bim   = (const float*)d_in[3];
    const float* Cre   = (const float*)d_in[4];
    const float* Cim   = (const float*)d_in[5];
    const float* Dv    = (const float*)d_in[6];
    const float* logdt = (const float*)d_in[7];
    float* out = (float*)d_out;

    lssl_kernel<<<dim3(H_DIM), dim3(NT), 0, stream>>>(
        Lre, Lim, Bre, Bim, Cre, Cim, Dv, logdt, out);
}